// Round 1
// baseline (14479.214 us; speedup 1.0000x reference)
//
#include <hip/hip_runtime.h>

// Farthest Point Sampling + gather for B=32, N=65536, S=512, C=64 (fp32).
//
// Correctness contract: distances must be computed BIT-EXACTLY like the numpy
// reference ( ((dx*dx + dy*dy) + dz*dz), no fma contraction ), argmax must
// pick the FIRST maximal index. Then selected indices match exactly and the
// gathered outputs are bit-equal to the reference.

#define BATCH 32
#define NPTS  65536
#define NSAMP 512
#define NCH   64
#define TPB   512                 // threads per FPS block
#define PPT   (NPTS / TPB)        // 128 points per thread

__global__ __launch_bounds__(TPB, 2) void fps_kernel(
    const float* __restrict__ xyz,   // [B, N, 3]
    float* __restrict__ out_xyz,     // [B, S, 3]
    int* __restrict__ idx_out)       // [B, S]
{
    const int b   = blockIdx.x;
    const int tid = threadIdx.x;
    const float* xb = xyz + (size_t)b * NPTS * 3;

    float dist[PPT];
#pragma unroll
    for (int i = 0; i < PPT; ++i) dist[i] = 1e10f;

    __shared__ float red_v[TPB / 64];
    __shared__ int   red_n[TPB / 64];
    __shared__ int   lds_far;

    int farthest = 0;

    for (int s = 0; s < NSAMP; ++s) {
        // Broadcast centroid coords (same address for all lanes -> L1 broadcast).
        const float* cp = xb + (size_t)farthest * 3;
        float cx = cp[0], cy = cp[1], cz = cp[2];

        // Record the incoming 'farthest' (scan semantics: idx[s] = carry before update).
        if (tid == 0) {
            idx_out[b * NSAMP + s] = farthest;
            float* o = out_xyz + ((size_t)b * NSAMP + s) * 3;
            o[0] = cx; o[1] = cy; o[2] = cz;
        }

        // Per-thread dist update + local argmax (first-index tie-break via strict >).
        float bv = -1.0f;
        int   bn = 0;
#pragma unroll
        for (int i = 0; i < PPT; ++i) {
            int n = i * TPB + tid;                 // increasing n within thread
            const float* p = xb + (size_t)n * 3;
            float dx = p[0] - cx;
            float dy = p[1] - cy;
            float dz = p[2] - cz;
            // numpy-exact: ((dx*dx + dy*dy) + dz*dz), contraction forbidden
            float d = __fadd_rn(__fadd_rn(__fmul_rn(dx, dx), __fmul_rn(dy, dy)),
                                __fmul_rn(dz, dz));
            float nd = fminf(dist[i], d);
            dist[i] = nd;
            if (nd > bv) { bv = nd; bn = n; }
        }

        // 64-lane wave reduce (max value, min index on ties).
#pragma unroll
        for (int off = 32; off >= 1; off >>= 1) {
            float pv = __shfl_down(bv, off, 64);
            int   pn = __shfl_down(bn, off, 64);
            if (pv > bv || (pv == bv && pn < bn)) { bv = pv; bn = pn; }
        }
        int wave = tid >> 6;
        if ((tid & 63) == 0) { red_v[wave] = bv; red_n[wave] = bn; }
        __syncthreads();
        if (tid == 0) {
            float fv = red_v[0]; int fn = red_n[0];
#pragma unroll
            for (int w = 1; w < TPB / 64; ++w) {
                float pv = red_v[w]; int pn = red_n[w];
                if (pv > fv || (pv == fv && pn < fn)) { fv = pv; fn = pn; }
            }
            lds_far = fn;
        }
        __syncthreads();
        farthest = lds_far;
        __syncthreads();   // protect red_v/red_n reuse next iteration
    }
}

__global__ void gather_f_kernel(
    const float* __restrict__ f,     // [B, N, C]
    const int* __restrict__ idx,     // [B, S]
    float* __restrict__ out_f)       // [B, S, C]
{
    const int s = blockIdx.x;
    const int b = blockIdx.y;
    const int c = threadIdx.x;
    int n = idx[b * NSAMP + s];
    out_f[((size_t)b * NSAMP + s) * NCH + c] = f[((size_t)b * NPTS + n) * NCH + c];
}

extern "C" void kernel_launch(void* const* d_in, const int* in_sizes, int n_in,
                              void* d_out, int out_size, void* d_ws, size_t ws_size,
                              hipStream_t stream) {
    const float* xyz = (const float*)d_in[0];   // [32, 65536, 3]
    const float* f   = (const float*)d_in[1];   // [32, 65536, 64]
    float* out_xyz = (float*)d_out;                              // [32, 512, 3]
    float* out_f   = (float*)d_out + (size_t)BATCH * NSAMP * 3;  // [32, 512, 64]
    int*   idx_ws  = (int*)d_ws;                                 // [32, 512]

    fps_kernel<<<BATCH, TPB, 0, stream>>>(xyz, out_xyz, idx_ws);
    gather_f_kernel<<<dim3(NSAMP, BATCH), NCH, 0, stream>>>(f, idx_ws, out_f);
}